// Round 1
// baseline (1942.800 us; speedup 1.0000x reference)
//
#include <hip/hip_runtime.h>
#include <math.h>

// Problem constants
constexpr int BB = 2;
constexpr int SS = 2048;
constexpr int EE = 1024;
constexpr int HH = 16;
constexpr int DD = 64;
constexpr int NSEG = 32;   // 2048 / 64 segments for the suffix scan

// ---------------------------------------------------------------------------
// Projection GEMM: C[n,o] = sum_j X[n,j] * W[o,j] + bias[o]
// X: [B*S, E] row-major, W: [E_out, E_in] row-major (we need x @ W.T).
// Output written in [B, H, S, D] layout for the attention stage.
// 64x64 block tile, 256 threads, 4x4 per-thread microtile, BK=16.
// ---------------------------------------------------------------------------
__global__ __launch_bounds__(256) void proj_kernel(
    const float* __restrict__ X, const float* __restrict__ W,
    const float* __restrict__ bias, float* __restrict__ out)
{
    __shared__ __align__(16) float As[16][68];  // As[k][m]
    __shared__ __align__(16) float Bs[16][68];  // Bs[k][n]
    const int t = threadIdx.x;
    const int row0 = blockIdx.x * 64;
    const int col0 = blockIdx.y * 64;
    const int lm = t >> 2;          // 0..63 (row within tile for loading)
    const int lk = (t & 3) << 2;    // 0,4,8,12 (k offset for loading)
    const int tm = (t & 15) << 2;   // output rows
    const int tn = (t >> 4) << 2;   // output cols

    float acc[4][4] = {};

    for (int k0 = 0; k0 < EE; k0 += 16) {
        float4 xa = *(const float4*)&X[(size_t)(row0 + lm) * EE + k0 + lk];
        float4 wa = *(const float4*)&W[(size_t)(col0 + lm) * EE + k0 + lk];
        __syncthreads();
        As[lk + 0][lm] = xa.x; As[lk + 1][lm] = xa.y;
        As[lk + 2][lm] = xa.z; As[lk + 3][lm] = xa.w;
        Bs[lk + 0][lm] = wa.x; Bs[lk + 1][lm] = wa.y;
        Bs[lk + 2][lm] = wa.z; Bs[lk + 3][lm] = wa.w;
        __syncthreads();
        #pragma unroll
        for (int kk = 0; kk < 16; ++kk) {
            float4 a4 = *(const float4*)&As[kk][tm];
            float4 b4 = *(const float4*)&Bs[kk][tn];
            float av[4] = {a4.x, a4.y, a4.z, a4.w};
            float bv[4] = {b4.x, b4.y, b4.z, b4.w};
            #pragma unroll
            for (int ii = 0; ii < 4; ++ii)
                #pragma unroll
                for (int jj = 0; jj < 4; ++jj)
                    acc[ii][jj] += av[ii] * bv[jj];
        }
    }

    #pragma unroll
    for (int ii = 0; ii < 4; ++ii) {
        const int n = row0 + tm + ii;
        const int b = n >> 11;          // n / S
        const int s = n & (SS - 1);
        #pragma unroll
        for (int jj = 0; jj < 4; ++jj) {
            const int o = col0 + tn + jj;
            const int h = o >> 6;       // o / D
            const int d = o & 63;
            out[(((size_t)(b * HH + h) * SS) + s) * DD + d] = acc[ii][jj] + bias[o];
        }
    }
}

// ---------------------------------------------------------------------------
// Suffix scan of V over S: Sv[b,h,i,d] = sum_{k>i} v[b,h,k,d]; Tot = full sum.
// ---------------------------------------------------------------------------
__global__ __launch_bounds__(64) void scan_partial(
    const float* __restrict__ v, float* __restrict__ Sv, float* __restrict__ segsum)
{
    const int blk = blockIdx.x;
    const int seg = blk & (NSEG - 1);
    const int bh  = blk >> 5;
    const int d   = threadIdx.x;
    const float* vp = v  + ((size_t)bh * SS + seg * 64) * DD + d;
    float*       sp = Sv + ((size_t)bh * SS + seg * 64) * DD + d;
    float run = 0.f;
    for (int s = 63; s >= 0; --s) { sp[s * DD] = run; run += vp[s * DD]; }
    segsum[(size_t)(bh * NSEG + seg) * DD + d] = run;
}

__global__ __launch_bounds__(64) void scan_finalize(
    float* __restrict__ Sv, const float* __restrict__ segsum, float* __restrict__ Tot)
{
    const int blk = blockIdx.x;
    const int seg = blk & (NSEG - 1);
    const int bh  = blk >> 5;
    const int d   = threadIdx.x;
    float off = 0.f;
    for (int c = seg + 1; c < NSEG; ++c)
        off += segsum[(size_t)(bh * NSEG + c) * DD + d];
    float* sp = Sv + ((size_t)bh * SS + seg * 64) * DD + d;
    for (int s = 0; s < 64; ++s) sp[s * DD] += off;
    if (seg == 0)
        Tot[bh * DD + d] = off + segsum[(size_t)(bh * NSEG) * DD + d];
}

// ---------------------------------------------------------------------------
// Causal attention with log-softmax decomposition.
// Per block: one (b,h) and one 64-row Q tile. Loop K tiles up to the diagonal.
//   acc[i,d]  = sum_{k<=i} L[i,k] * V[k,d]   (raw logits, linear in L)
//   lse_i     = online logsumexp over unmasked L[i,k]
//   out[i,d]  = acc - lse_i*Tot[d] - 1e9*Sv[i,d]
// ---------------------------------------------------------------------------
__global__ __launch_bounds__(256) void attn_kernel(
    const float* __restrict__ q, const float* __restrict__ k,
    const float* __restrict__ v, const float* __restrict__ Sv,
    const float* __restrict__ Tot, const float* __restrict__ pb,
    float* __restrict__ out)
{
    __shared__ __align__(16) float Qs[64][68];
    __shared__ __align__(16) float Ks[64][68];
    __shared__ __align__(16) float Vs[64][68];
    __shared__ __align__(16) float Ls[64][68];
    __shared__ float pm[4][64], ps[4][64];
    __shared__ float mrow[64], srow[64];

    const int t  = threadIdx.x;
    const int qt = blockIdx.x;       // Q tile index (0..31)
    const int bh = blockIdx.y;       // 0..31
    const int b  = bh >> 4;
    const int h  = bh & 15;
    const int i0 = qt * 64;
    const float* qp = q + (size_t)bh * SS * DD;
    const float* kp = k + (size_t)bh * SS * DD;
    const float* vp = v + (size_t)bh * SS * DD;
    const int tm = (t & 15) << 2;    // rows (i) for this thread
    const int tn = (t >> 4) << 2;    // cols (k or d) for this thread

    // Load Q tile (64 rows x 64 cols)
    #pragma unroll
    for (int f = 0; f < 4; ++f) {
        const int idx = t * 4 + f;
        const int r = idx >> 4;
        const int c = (idx & 15) << 2;
        *(float4*)&Qs[r][c] = *(const float4*)&qp[(size_t)(i0 + r) * DD + c];
    }
    if (t < 64) { mrow[t] = -1e30f; srow[t] = 0.f; }

    float acc[4][4] = {};

    for (int kt = 0; kt <= qt; ++kt) {
        const int k0 = kt * 64;
        float4 kreg[4], vreg[4];
        #pragma unroll
        for (int f = 0; f < 4; ++f) {
            const int idx = t * 4 + f;
            const int r = idx >> 4;
            const int c = (idx & 15) << 2;
            kreg[f] = *(const float4*)&kp[(size_t)(k0 + r) * DD + c];
            vreg[f] = *(const float4*)&vp[(size_t)(k0 + r) * DD + c];
        }
        __syncthreads();   // previous iteration's consumers of Ks/Vs/Ls done
        #pragma unroll
        for (int f = 0; f < 4; ++f) {
            const int idx = t * 4 + f;
            const int r = idx >> 4;
            const int c = (idx & 15) << 2;
            *(float4*)&Ks[r][c] = kreg[f];
            *(float4*)&Vs[r][c] = vreg[f];
        }
        __syncthreads();

        // QK^T for this thread's 4x4 (rows tm.., cols tn..)
        float accl[4][4] = {};
        for (int c = 0; c < 64; c += 4) {
            float4 qv[4], kv[4];
            #pragma unroll
            for (int ii = 0; ii < 4; ++ii) qv[ii] = *(const float4*)&Qs[tm + ii][c];
            #pragma unroll
            for (int jj = 0; jj < 4; ++jj) kv[jj] = *(const float4*)&Ks[tn + jj][c];
            #pragma unroll
            for (int ii = 0; ii < 4; ++ii)
                #pragma unroll
                for (int jj = 0; jj < 4; ++jj)
                    accl[ii][jj] += qv[ii].x * kv[jj].x + qv[ii].y * kv[jj].y
                                  + qv[ii].z * kv[jj].z + qv[ii].w * kv[jj].w;
        }
        // scale + pos_bias + causal mask (masked -> 0, excluded from lse)
        #pragma unroll
        for (int ii = 0; ii < 4; ++ii) {
            const int ig = i0 + tm + ii;
            #pragma unroll
            for (int jj = 0; jj < 4; ++jj) {
                const int kg = k0 + tn + jj;
                float val = 0.f;
                if (kg <= ig)
                    val = accl[ii][jj] * 0.125f + pb[h * (2 * SS - 1) + (ig - kg + SS - 1)];
                Ls[tm + ii][tn + jj] = val;
            }
        }
        __syncthreads();

        // Online lse: 4 partials per row (one per 16-col segment), then combine
        {
            const int r  = t & 63;
            const int w  = t >> 6;
            const int cs = w * 16;
            const int cmax = (kt < qt) ? 63 : r;   // causal bound within tile
            float lm = -1e30f, lsum = 0.f;
            const int ce = (cs + 15 < cmax) ? (cs + 15) : cmax;
            for (int c = cs; c <= ce; ++c) {
                const float x = Ls[r][c];
                if (x > lm) { lsum *= __expf(lm - x); lm = x; }
                lsum += __expf(x - lm);
            }
            pm[w][r] = lm; ps[w][r] = lsum;
        }
        __syncthreads();
        if (t < 64) {
            float m = mrow[t], ssum = srow[t];
            #pragma unroll
            for (int w = 0; w < 4; ++w) {
                const float lm2 = pm[w][t], ls2 = ps[w][t];
                const float mn = fmaxf(m, lm2);
                if (mn > -1e29f)
                    ssum = ssum * __expf(m - mn) + ls2 * __expf(lm2 - mn);
                m = mn;
            }
            mrow[t] = m; srow[t] = ssum;
        }

        // PV: acc[ii][dd] += Ls[tm+ii][kk] * Vs[kk][tn+dd]
        for (int kk = 0; kk < 64; kk += 4) {
            float lvf[4][4], vvf[4][4];
            #pragma unroll
            for (int ii = 0; ii < 4; ++ii) {
                float4 tmp = *(const float4*)&Ls[tm + ii][kk];
                lvf[ii][0] = tmp.x; lvf[ii][1] = tmp.y; lvf[ii][2] = tmp.z; lvf[ii][3] = tmp.w;
            }
            #pragma unroll
            for (int j = 0; j < 4; ++j) {
                float4 tmp = *(const float4*)&Vs[kk + j][tn];
                vvf[j][0] = tmp.x; vvf[j][1] = tmp.y; vvf[j][2] = tmp.z; vvf[j][3] = tmp.w;
            }
            #pragma unroll
            for (int ii = 0; ii < 4; ++ii)
                #pragma unroll
                for (int jj = 0; jj < 4; ++jj)
                    acc[ii][jj] += lvf[ii][0] * vvf[0][jj] + lvf[ii][1] * vvf[1][jj]
                                 + lvf[ii][2] * vvf[2][jj] + lvf[ii][3] * vvf[3][jj];
        }
    }
    __syncthreads();

    // Epilogue: combine the three terms
    #pragma unroll
    for (int ii = 0; ii < 4; ++ii) {
        const int r  = tm + ii;
        const int ig = i0 + r;
        const float lse = mrow[r] + logf(srow[r]);
        #pragma unroll
        for (int jj = 0; jj < 4; ++jj) {
            const int d = tn + jj;
            const float o = acc[ii][jj]
                          - lse * Tot[bh * DD + d]
                          - 1e9f * Sv[((size_t)bh * SS + ig) * DD + d];
            out[((size_t)(b * SS + ig)) * EE + h * DD + d] = o;
        }
    }
}

// ---------------------------------------------------------------------------
extern "C" void kernel_launch(void* const* d_in, const int* in_sizes, int n_in,
                              void* d_out, int out_size, void* d_ws, size_t ws_size,
                              hipStream_t stream)
{
    const float* query = (const float*)d_in[0];
    const float* key_  = (const float*)d_in[1];
    const float* value = (const float*)d_in[2];
    const float* Wq = (const float*)d_in[3];
    const float* bq = (const float*)d_in[4];
    const float* Wk = (const float*)d_in[5];
    const float* bk = (const float*)d_in[6];
    const float* Wv = (const float*)d_in[7];
    const float* bv = (const float*)d_in[8];
    const float* pb = (const float*)d_in[9];
    // d_in[10..12] (idx0, idx1, mask) are deterministic; recomputed on the fly.
    float* out = (float*)d_out;

    float* ws = (float*)d_ws;
    const size_t SZ = (size_t)BB * SS * EE;   // 4M floats per tensor
    float* qb   = ws;
    float* kb   = ws + SZ;
    float* vb   = ws + 2 * SZ;
    float* Svb  = ws + 3 * SZ;
    float* Totb = ws + 4 * SZ;                       // B*H*D floats
    float* segs = Totb + (size_t)BB * HH * DD;       // B*H*NSEG*D floats

    dim3 pgrid(BB * SS / 64, EE / 64);
    proj_kernel<<<pgrid, 256, 0, stream>>>(query, Wq, bq, qb);
    proj_kernel<<<pgrid, 256, 0, stream>>>(key_,  Wk, bk, kb);
    proj_kernel<<<pgrid, 256, 0, stream>>>(value, Wv, bv, vb);

    scan_partial<<<BB * HH * NSEG, 64, 0, stream>>>(vb, Svb, segs);
    scan_finalize<<<BB * HH * NSEG, 64, 0, stream>>>(Svb, segs, Totb);

    attn_kernel<<<dim3(SS / 64, BB * HH), 256, 0, stream>>>(qb, kb, vb, Svb, Totb, pb, out);
}

// Round 2
// 358.445 us; speedup vs baseline: 5.4201x; 5.4201x over previous
//
#include <hip/hip_runtime.h>
#include <math.h>

constexpr int BB = 2;
constexpr int SS = 2048;
constexpr int EE = 1024;
constexpr int HH = 16;
constexpr int DD = 64;
constexpr int NSEG = 32;

typedef short short8 __attribute__((ext_vector_type(8)));
typedef short short4_t __attribute__((ext_vector_type(4)));
typedef float floatx4 __attribute__((ext_vector_type(4)));

__device__ __forceinline__ unsigned short f2bf(float f) {
    unsigned int u = __float_as_uint(f);
    u += 0x7fffu + ((u >> 16) & 1u);   // RNE
    return (unsigned short)(u >> 16);
}

// ---------------------------------------------------------------------------
// Fused 3-way projection GEMM (bf16 MFMA): C = X @ W^T + b, written [B,H,S,D].
// 128x128 tile, BK=32, 256 threads (4 waves, each 64x64 = 4x4 MFMA tiles).
// ---------------------------------------------------------------------------
__global__ __launch_bounds__(256) void proj_kernel(
    const float* __restrict__ Xq, const float* __restrict__ Wq, const float* __restrict__ bq, float* __restrict__ dq,
    const float* __restrict__ Xk, const float* __restrict__ Wk, const float* __restrict__ bk, float* __restrict__ dk,
    const float* __restrict__ Xv, const float* __restrict__ Wv, const float* __restrict__ bv, float* __restrict__ dv)
{
    __shared__ __align__(16) unsigned short As[128 * 40];
    __shared__ __align__(16) unsigned short Bs[128 * 40];

    const float *X, *W, *bias; float* dst;
    if (blockIdx.z == 0)      { X = Xq; W = Wq; bias = bq; dst = dq; }
    else if (blockIdx.z == 1) { X = Xk; W = Wk; bias = bk; dst = dk; }
    else                      { X = Xv; W = Wv; bias = bv; dst = dv; }

    const int t = threadIdx.x;
    const int row0 = blockIdx.x * 128;
    const int col0 = blockIdx.y * 128;
    const int w  = t >> 6;
    const int ln = t & 15;
    const int qd = (t >> 4) & 3;
    const int wm = (w & 1) * 64;
    const int wn = (w >> 1) * 64;
    const int sr = t >> 3;          // staging row-within-32
    const int sc = (t & 7) * 4;     // staging col

    floatx4 acc[4][4];
    #pragma unroll
    for (int i = 0; i < 4; ++i)
        #pragma unroll
        for (int j = 0; j < 4; ++j)
            acc[i][j] = (floatx4){0.f, 0.f, 0.f, 0.f};

    for (int k0 = 0; k0 < EE; k0 += 32) {
        __syncthreads();
        #pragma unroll
        for (int q = 0; q < 4; ++q) {
            const int r = q * 32 + sr;
            float4 xa = *(const float4*)&X[(size_t)(row0 + r) * EE + k0 + sc];
            float4 wa = *(const float4*)&W[(size_t)(col0 + r) * EE + k0 + sc];
            short4_t pa, pb2;
            pa[0] = (short)f2bf(xa.x); pa[1] = (short)f2bf(xa.y);
            pa[2] = (short)f2bf(xa.z); pa[3] = (short)f2bf(xa.w);
            pb2[0] = (short)f2bf(wa.x); pb2[1] = (short)f2bf(wa.y);
            pb2[2] = (short)f2bf(wa.z); pb2[3] = (short)f2bf(wa.w);
            *(short4_t*)&As[r * 40 + sc] = pa;
            *(short4_t*)&Bs[r * 40 + sc] = pb2;
        }
        __syncthreads();

        short8 af[4], bf[4];
        #pragma unroll
        for (int mi = 0; mi < 4; ++mi)
            af[mi] = *(const short8*)&As[(wm + mi * 16 + ln) * 40 + qd * 8];
        #pragma unroll
        for (int ni = 0; ni < 4; ++ni)
            bf[ni] = *(const short8*)&Bs[(wn + ni * 16 + ln) * 40 + qd * 8];
        #pragma unroll
        for (int mi = 0; mi < 4; ++mi)
            #pragma unroll
            for (int ni = 0; ni < 4; ++ni)
                acc[mi][ni] = __builtin_amdgcn_mfma_f32_16x16x32_bf16(af[mi], bf[ni], acc[mi][ni], 0, 0, 0);
    }

    // Epilogue: C rows = (lane>>4)*4+reg (A-row), cols = lane&15 (B-row/W-row)
    #pragma unroll
    for (int ni = 0; ni < 4; ++ni) {
        const int coln = col0 + wn + ni * 16 + ln;
        const float bvv = bias[coln];
        const int h = coln >> 6, d = coln & 63;
        #pragma unroll
        for (int mi = 0; mi < 4; ++mi) {
            #pragma unroll
            for (int reg = 0; reg < 4; ++reg) {
                const int row = row0 + wm + mi * 16 + qd * 4 + reg;
                const int b = row >> 11, s = row & (SS - 1);
                dst[(((size_t)(b * HH + h) * SS) + s) * DD + d] = acc[mi][ni][reg] + bvv;
            }
        }
    }
}

// ---------------------------------------------------------------------------
// Suffix scan of V over S (exact fp32): Sv[i] = sum_{k>i} v[k]; Tot = full sum.
// ---------------------------------------------------------------------------
__global__ __launch_bounds__(64) void scan_partial(
    const float* __restrict__ v, float* __restrict__ Sv, float* __restrict__ segsum)
{
    const int blk = blockIdx.x;
    const int seg = blk & (NSEG - 1);
    const int bh  = blk >> 5;
    const int d   = threadIdx.x;
    const float* vp = v  + ((size_t)bh * SS + seg * 64) * DD + d;
    float*       sp = Sv + ((size_t)bh * SS + seg * 64) * DD + d;
    float run = 0.f;
    for (int s = 63; s >= 0; --s) { sp[s * DD] = run; run += vp[s * DD]; }
    segsum[(size_t)(bh * NSEG + seg) * DD + d] = run;
}

__global__ __launch_bounds__(64) void scan_finalize(
    float* __restrict__ Sv, const float* __restrict__ segsum, float* __restrict__ Tot)
{
    const int blk = blockIdx.x;
    const int seg = blk & (NSEG - 1);
    const int bh  = blk >> 5;
    const int d   = threadIdx.x;
    float off = 0.f;
    for (int c = seg + 1; c < NSEG; ++c)
        off += segsum[(size_t)(bh * NSEG + c) * DD + d];
    float* sp = Sv + ((size_t)bh * SS + seg * 64) * DD + d;
    for (int s = 0; s < 64; ++s) sp[s * DD] += off;
    if (seg == 0)
        Tot[bh * DD + d] = off + segsum[(size_t)(bh * NSEG) * DD + d];
}

// ---------------------------------------------------------------------------
// MFMA causal attention, log-softmax decomposition:
//   out[i,d] = sum_{k<=i} L[i,k] v[k,d]  -  lse_i * Tot[d]  -  1e9 * Sv[i,d]
// Block: 128 Q rows for one (b,h); 4 waves x 32 rows; K-tiles of 64.
// No max-tracking in lse: |L| <~ 25 so sum(exp) < 1e14, no fp32 overflow.
// ---------------------------------------------------------------------------
__global__ __launch_bounds__(256) void attn_kernel(
    const float* __restrict__ q, const float* __restrict__ k,
    const float* __restrict__ v, const float* __restrict__ Sv,
    const float* __restrict__ Tot, const float* __restrict__ pb,
    float* __restrict__ out)
{
    __shared__ __align__(16) unsigned short Ks[64 * 72];   // [k][d] bf16
    __shared__ __align__(16) unsigned short Vt[64 * 72];   // [d][k] bf16 (transposed)
    __shared__ __align__(16) unsigned short Ls[128 * 72];  // [i][k] bf16, wave-private rows
    __shared__ float pbs[192];

    const int t  = threadIdx.x;
    const int id = blockIdx.x;
    const int bh = id & 31;
    const int tt = id >> 5;
    const int qt = (tt < 8) ? (15 - tt) : (tt - 8);   // heavy-first, paired load balance
    const int b  = bh >> 4, h = bh & 15;
    const int i0 = qt * 128;
    const int w  = t >> 6;
    const int ln = t & 15;
    const int qd = (t >> 4) & 3;

    const float* qp = q + (size_t)bh * SS * DD;
    const float* kp = k + (size_t)bh * SS * DD;
    const float* vp = v + (size_t)bh * SS * DD;

    // Q fragments (A-operand, invariant over K loop): rows 32w+16mt+ln
    short8 qf[2][2];
    #pragma unroll
    for (int mt = 0; mt < 2; ++mt)
        #pragma unroll
        for (int kh = 0; kh < 2; ++kh) {
            const float* qr = qp + (size_t)(i0 + 32 * w + 16 * mt + ln) * DD + kh * 32 + qd * 8;
            float4 x0 = *(const float4*)qr;
            float4 x1 = *(const float4*)(qr + 4);
            short8 f;
            f[0] = (short)f2bf(x0.x); f[1] = (short)f2bf(x0.y);
            f[2] = (short)f2bf(x0.z); f[3] = (short)f2bf(x0.w);
            f[4] = (short)f2bf(x1.x); f[5] = (short)f2bf(x1.y);
            f[6] = (short)f2bf(x1.z); f[7] = (short)f2bf(x1.w);
            qf[mt][kh] = f;
        }

    floatx4 accpv[2][4];
    #pragma unroll
    for (int mt = 0; mt < 2; ++mt)
        #pragma unroll
        for (int ct = 0; ct < 4; ++ct)
            accpv[mt][ct] = (floatx4){0.f, 0.f, 0.f, 0.f};
    float part[2][4] = {};

    const int nkt = 2 * qt + 2;
    for (int kt = 0; kt < nkt; ++kt) {
        const int k0 = kt * 64;
        __syncthreads();   // prior iteration's Ks/Vt readers done

        // Stage K tile [k][d] bf16 (row-major, uniform banks)
        {
            const int kr = t >> 2, db = (t & 3) * 16;
            const float* src = kp + (size_t)(k0 + kr) * DD + db;
            float4 x0 = *(const float4*)(src);
            float4 x1 = *(const float4*)(src + 4);
            float4 x2 = *(const float4*)(src + 8);
            float4 x3 = *(const float4*)(src + 12);
            short8 p0, p1;
            p0[0] = (short)f2bf(x0.x); p0[1] = (short)f2bf(x0.y); p0[2] = (short)f2bf(x0.z); p0[3] = (short)f2bf(x0.w);
            p0[4] = (short)f2bf(x1.x); p0[5] = (short)f2bf(x1.y); p0[6] = (short)f2bf(x1.z); p0[7] = (short)f2bf(x1.w);
            p1[0] = (short)f2bf(x2.x); p1[1] = (short)f2bf(x2.y); p1[2] = (short)f2bf(x2.z); p1[3] = (short)f2bf(x2.w);
            p1[4] = (short)f2bf(x3.x); p1[5] = (short)f2bf(x3.y); p1[6] = (short)f2bf(x3.z); p1[7] = (short)f2bf(x3.w);
            *(short8*)&Ks[kr * 72 + db]     = p0;
            *(short8*)&Ks[kr * 72 + db + 8] = p1;
        }
        // Stage V transposed [d][k]: lane owns column d, reads 16 consecutive k
        // (each scalar load instr: 64 lanes x 4B consecutive = coalesced 256B)
        {
            const int dcol = t & 63, kb = (t >> 6) * 16;
            const float* src = vp + (size_t)(k0 + kb) * DD + dcol;
            short8 p0, p1;
            #pragma unroll
            for (int kk = 0; kk < 8; ++kk) p0[kk] = (short)f2bf(src[kk * DD]);
            #pragma unroll
            for (int kk = 0; kk < 8; ++kk) p1[kk] = (short)f2bf(src[(kk + 8) * DD]);
            *(short8*)&Vt[dcol * 72 + kb]     = p0;
            *(short8*)&Vt[dcol * 72 + kb + 8] = p1;
        }
        // Stage pos_bias slice: rel offsets d = ig-kg in [i0-k0-63, i0-k0+127]
        if (t < 191) pbs[t] = pb[h * (2 * SS - 1) + (i0 - k0 - 63 + t) + (SS - 1)];
        __syncthreads();

        // QK^T: per wave 2 row-tiles x 4 col-tiles, K=64 via 2 mfma
        floatx4 aq[2][4];
        #pragma unroll
        for (int mt = 0; mt < 2; ++mt)
            #pragma unroll
            for (int ct = 0; ct < 4; ++ct)
                aq[mt][ct] = (floatx4){0.f, 0.f, 0.f, 0.f};
        #pragma unroll
        for (int kh = 0; kh < 2; ++kh) {
            short8 bf[4];
            #pragma unroll
            for (int ct = 0; ct < 4; ++ct)
                bf[ct] = *(const short8*)&Ks[(ct * 16 + ln) * 72 + kh * 32 + qd * 8];
            #pragma unroll
            for (int mt = 0; mt < 2; ++mt)
                #pragma unroll
                for (int ct = 0; ct < 4; ++ct)
                    aq[mt][ct] = __builtin_amdgcn_mfma_f32_16x16x32_bf16(qf[mt][kh], bf[ct], aq[mt][ct], 0, 0, 0);
        }

        // scale + pos_bias + causal mask; accumulate exp; write P (bf16) to Ls
        #pragma unroll
        for (int mt = 0; mt < 2; ++mt)
            #pragma unroll
            for (int ct = 0; ct < 4; ++ct) {
                const int krel = ct * 16 + ln;          // kg - k0
                const int kg = k0 + krel;
                #pragma unroll
                for (int reg = 0; reg < 4; ++reg) {
                    const int irel = 32 * w + 16 * mt + qd * 4 + reg;  // ig - i0
                    const int ig = i0 + irel;
                    const float val = aq[mt][ct][reg] * 0.125f + pbs[irel - krel + 63];
                    const bool ok = (kg <= ig);
                    part[mt][reg] += ok ? __expf(val) : 0.f;
                    Ls[irel * 72 + krel] = ok ? f2bf(val) : (unsigned short)0;
                }
            }

        // PV: A = Ls rows (wave-private: intra-wave DS ordering, no barrier)
        #pragma unroll
        for (int kh = 0; kh < 2; ++kh) {
            short8 af[2], bf[4];
            #pragma unroll
            for (int mt = 0; mt < 2; ++mt)
                af[mt] = *(const short8*)&Ls[(32 * w + 16 * mt + ln) * 72 + kh * 32 + qd * 8];
            #pragma unroll
            for (int ct = 0; ct < 4; ++ct)
                bf[ct] = *(const short8*)&Vt[(ct * 16 + ln) * 72 + kh * 32 + qd * 8];
            #pragma unroll
            for (int mt = 0; mt < 2; ++mt)
                #pragma unroll
                for (int ct = 0; ct < 4; ++ct)
                    accpv[mt][ct] = __builtin_amdgcn_mfma_f32_16x16x32_bf16(af[mt], bf[ct], accpv[mt][ct], 0, 0, 0);
        }
    }

    // Row lse: reduce exp-partials over the 16 lanes sharing a row
    float lse[2][4];
    #pragma unroll
    for (int mt = 0; mt < 2; ++mt)
        #pragma unroll
        for (int reg = 0; reg < 4; ++reg) {
            float p = part[mt][reg];
            p += __shfl_xor(p, 1, 64);
            p += __shfl_xor(p, 2, 64);
            p += __shfl_xor(p, 4, 64);
            p += __shfl_xor(p, 8, 64);
            lse[mt][reg] = __logf(p);
        }

    float tot[4];
    #pragma unroll
    for (int ct = 0; ct < 4; ++ct) tot[ct] = Tot[bh * DD + ct * 16 + ln];

    #pragma unroll
    for (int mt = 0; mt < 2; ++mt)
        #pragma unroll
        for (int ct = 0; ct < 4; ++ct) {
            const int d = ct * 16 + ln;
            #pragma unroll
            for (int reg = 0; reg < 4; ++reg) {
                const int ig = i0 + 32 * w + 16 * mt + qd * 4 + reg;
                const float sv = Sv[((size_t)bh * SS + ig) * DD + d];
                const float o = accpv[mt][ct][reg] - lse[mt][reg] * tot[ct] - 1e9f * sv;
                out[((size_t)(b * SS + ig)) * EE + h * DD + d] = o;
            }
        }
}

// ---------------------------------------------------------------------------
extern "C" void kernel_launch(void* const* d_in, const int* in_sizes, int n_in,
                              void* d_out, int out_size, void* d_ws, size_t ws_size,
                              hipStream_t stream)
{
    const float* query = (const float*)d_in[0];
    const float* key_  = (const float*)d_in[1];
    const float* value = (const float*)d_in[2];
    const float* Wq = (const float*)d_in[3];
    const float* bq = (const float*)d_in[4];
    const float* Wk = (const float*)d_in[5];
    const float* bk = (const float*)d_in[6];
    const float* Wv = (const float*)d_in[7];
    const float* bv = (const float*)d_in[8];
    const float* pb = (const float*)d_in[9];
    float* out = (float*)d_out;

    float* ws = (float*)d_ws;
    const size_t SZ = (size_t)BB * SS * EE;
    float* qb   = ws;
    float* kb   = ws + SZ;
    float* vb   = ws + 2 * SZ;
    float* Svb  = ws + 3 * SZ;
    float* Totb = ws + 4 * SZ;
    float* segs = Totb + (size_t)BB * HH * DD;

    proj_kernel<<<dim3(BB * SS / 128, EE / 128, 3), 256, 0, stream>>>(
        query, Wq, bq, qb,  key_, Wk, bk, kb,  value, Wv, bv, vb);

    scan_partial<<<BB * HH * NSEG, 64, 0, stream>>>(vb, Svb, segs);
    scan_finalize<<<BB * HH * NSEG, 64, 0, stream>>>(Svb, segs, Totb);

    attn_kernel<<<BB * HH * (SS / 128), 256, 0, stream>>>(qb, kb, vb, Svb, Totb, pb, out);
}

// Round 3
// 258.193 us; speedup vs baseline: 7.5246x; 1.3883x over previous
//
#include <hip/hip_runtime.h>
#include <math.h>

constexpr int BB = 2;
constexpr int SS = 2048;
constexpr int EE = 1024;
constexpr int HH = 16;
constexpr int DD = 64;
constexpr int NSEG = 32;

typedef short short8 __attribute__((ext_vector_type(8)));
typedef short short4_t __attribute__((ext_vector_type(4)));
typedef float floatx4 __attribute__((ext_vector_type(4)));
typedef unsigned short ushort_t;

__device__ __forceinline__ ushort_t f2bf(float f) {
    unsigned int u = __float_as_uint(f);
    u += 0x7fffu + ((u >> 16) & 1u);   // RNE
    return (ushort_t)(u >> 16);
}

// async global->LDS, 16 B per lane; LDS dest = uniform base + lane*16
__device__ __forceinline__ void gl_lds16(const void* g, void* l) {
    __builtin_amdgcn_global_load_lds(
        (const __attribute__((address_space(1))) void*)g,
        (__attribute__((address_space(3))) void*)l, 16, 0, 0);
}

// ---------------------------------------------------------------------------
// fp32 -> bf16 repack with XOR-group swizzle: within each aligned 64-col block,
// group-of-8 g goes to phys slot g ^ (row&7). One 8-elem group per thread.
// ---------------------------------------------------------------------------
__global__ __launch_bounds__(256) void repack_kernel(
    const float* __restrict__ s0, const float* __restrict__ s1, const float* __restrict__ s2,
    ushort_t* __restrict__ dst, int rows)
{
    const float* src = (blockIdx.z == 0) ? s0 : (blockIdx.z == 1) ? s1 : s2;
    ushort_t* d = dst + (size_t)blockIdx.z * rows * EE;
    const int idx = blockIdx.x * 256 + threadIdx.x;   // group id
    const int row = idx >> 7;                          // 128 groups per row (E=1024)
    const int gir = idx & 127;
    const int blk = gir >> 3, g = gir & 7;
    const int gp = g ^ (row & 7);
    const float* sp = src + (size_t)row * EE + gir * 8;
    float4 a = *(const float4*)sp;
    float4 b = *(const float4*)(sp + 4);
    short8 o;
    o[0] = (short)f2bf(a.x); o[1] = (short)f2bf(a.y); o[2] = (short)f2bf(a.z); o[3] = (short)f2bf(a.w);
    o[4] = (short)f2bf(b.x); o[5] = (short)f2bf(b.y); o[6] = (short)f2bf(b.z); o[7] = (short)f2bf(b.w);
    *(short8*)&d[(size_t)row * EE + blk * 64 + gp * 8] = o;
}

// ---------------------------------------------------------------------------
// bf16 projection GEMM, m97-style: 128x128 tile, BK=64, global_load_lds staging.
// z=0: q = X@Wq^T+b (swapped operands -> d-packed [bh][s][d] bf16 swizzled)
// z=1: k likewise; z=2: v -> fp32 [bh][s][d] (for scan) + bf16 vt [bh][d][s] swizzled
// ---------------------------------------------------------------------------
__global__ __launch_bounds__(256) void proj_kernel(
    const ushort_t* __restrict__ Xall, const ushort_t* __restrict__ Wall,
    const float* __restrict__ bq, const float* __restrict__ bk, const float* __restrict__ bv,
    ushort_t* __restrict__ qb, ushort_t* __restrict__ kbb,
    float* __restrict__ vf, ushort_t* __restrict__ vtb)
{
    __shared__ __align__(16) ushort_t Xs[128 * 64];
    __shared__ __align__(16) ushort_t Ws[128 * 64];

    const int z = blockIdx.z;
    const ushort_t* X = Xall + (size_t)z * BB * SS * EE;
    const ushort_t* W = Wall + (size_t)z * EE * EE;
    const float* bias = (z == 0) ? bq : (z == 1) ? bk : bv;

    const int t = threadIdx.x, w = t >> 6, l = t & 63, ln = t & 15, qd = (t >> 4) & 3;
    const int row0 = blockIdx.x * 128;   // X rows
    const int col0 = blockIdx.y * 128;   // W rows (outputs)
    const int wzm = (w & 1) * 64, wzn = (w >> 1) * 64;

    floatx4 acc[4][4];
    #pragma unroll
    for (int i = 0; i < 4; ++i)
        #pragma unroll
        for (int j = 0; j < 4; ++j)
            acc[i][j] = (floatx4){0.f, 0.f, 0.f, 0.f};

    for (int k0 = 0; k0 < EE; k0 += 64) {
        __syncthreads();   // prior-iter readers done before overwrite
        #pragma unroll
        for (int j = 0; j < 4; ++j) {
            const int c = w * 4 + j;          // 16 chunks of 8 rows each
            const int r = c * 8 + (l >> 3);
            gl_lds16(&X[(size_t)(row0 + r) * EE + k0 + (l & 7) * 8], &Xs[c * 512]);
            gl_lds16(&W[(size_t)(col0 + r) * EE + k0 + (l & 7) * 8], &Ws[c * 512]);
        }
        __syncthreads();   // drains vmcnt -> tiles ready

        const ushort_t* Am = (z < 2) ? Ws : Xs;   // m-dim operand
        const ushort_t* Bn = (z < 2) ? Xs : Ws;   // n-dim operand
        #pragma unroll
        for (int kh = 0; kh < 2; ++kh) {
            const int sw = ((kh * 4 + qd) ^ (ln & 7)) * 8;
            short8 af[4], bfr[4];
            #pragma unroll
            for (int mi = 0; mi < 4; ++mi)
                af[mi] = *(const short8*)&Am[(wzm + mi * 16 + ln) * 64 + sw];
            #pragma unroll
            for (int ni = 0; ni < 4; ++ni)
                bfr[ni] = *(const short8*)&Bn[(wzn + ni * 16 + ln) * 64 + sw];
            #pragma unroll
            for (int mi = 0; mi < 4; ++mi)
                #pragma unroll
                for (int ni = 0; ni < 4; ++ni)
                    acc[mi][ni] = __builtin_amdgcn_mfma_f32_16x16x32_bf16(af[mi], bfr[ni], acc[mi][ni], 0, 0, 0);
        }
    }

    if (z < 2) {
        // m = o (output col, 4 consecutive per reg-quad), n = s
        ushort_t* dst = z ? kbb : qb;
        #pragma unroll
        for (int mi = 0; mi < 4; ++mi) {
            const int o0 = col0 + wzm + mi * 16 + qd * 4;
            const float4 b4 = *(const float4*)&bias[o0];
            const int h = o0 >> 6, d0 = o0 & 63;
            const int g = d0 >> 3, dlow = d0 & 7;
            #pragma unroll
            for (int ni = 0; ni < 4; ++ni) {
                const int s = row0 + wzn + ni * 16 + ln;
                const int b = s >> 11, sr = s & (SS - 1);
                const int gp = g ^ (sr & 7);
                short4_t pk;
                pk[0] = (short)f2bf(acc[mi][ni][0] + b4.x);
                pk[1] = (short)f2bf(acc[mi][ni][1] + b4.y);
                pk[2] = (short)f2bf(acc[mi][ni][2] + b4.z);
                pk[3] = (short)f2bf(acc[mi][ni][3] + b4.w);
                *(short4_t*)&dst[((size_t)((b * HH + h) * SS) + sr) * DD + gp * 8 + dlow] = pk;
            }
        }
    } else {
        // m = s (4 consecutive per reg-quad), n = o
        #pragma unroll
        for (int mi = 0; mi < 4; ++mi) {
            const int s0 = row0 + wzm + mi * 16 + qd * 4;
            const int b = s0 >> 11, sr0 = s0 & (SS - 1);
            const int sg = (sr0 >> 3) & 7, slow = sr0 & 7;
            #pragma unroll
            for (int ni = 0; ni < 4; ++ni) {
                const int o = col0 + wzn + ni * 16 + ln;
                const int h = o >> 6, d = o & 63;
                const float bvv = bias[o];
                float v0 = acc[mi][ni][0] + bvv, v1 = acc[mi][ni][1] + bvv;
                float v2 = acc[mi][ni][2] + bvv, v3 = acc[mi][ni][3] + bvv;
                float* vp = &vf[((size_t)((b * HH + h) * SS) + sr0) * DD + d];
                vp[0 * DD] = v0; vp[1 * DD] = v1; vp[2 * DD] = v2; vp[3 * DD] = v3;
                const int gp2 = sg ^ (d & 7);
                short4_t pk;
                pk[0] = (short)f2bf(v0); pk[1] = (short)f2bf(v1);
                pk[2] = (short)f2bf(v2); pk[3] = (short)f2bf(v3);
                *(short4_t*)&vtb[((size_t)((b * HH + h) * DD) + d) * SS + (sr0 & ~63) + gp2 * 8 + slow] = pk;
            }
        }
    }
}

// ---------------------------------------------------------------------------
// Suffix scan of V over S (exact fp32): Sv[i] = sum_{k>i} v[k]; Tot = full sum.
// ---------------------------------------------------------------------------
__global__ __launch_bounds__(64) void scan_partial(
    const float* __restrict__ v, float* __restrict__ Sv, float* __restrict__ segsum)
{
    const int blk = blockIdx.x;
    const int seg = blk & (NSEG - 1);
    const int bh  = blk >> 5;
    const int d   = threadIdx.x;
    const float* vp = v  + ((size_t)bh * SS + seg * 64) * DD + d;
    float*       sp = Sv + ((size_t)bh * SS + seg * 64) * DD + d;
    float run = 0.f;
    for (int s = 63; s >= 0; --s) { sp[s * DD] = run; run += vp[s * DD]; }
    segsum[(size_t)(bh * NSEG + seg) * DD + d] = run;
}

__global__ __launch_bounds__(64) void scan_finalize(
    float* __restrict__ Sv, const float* __restrict__ segsum, float* __restrict__ Tot)
{
    const int blk = blockIdx.x;
    const int seg = blk & (NSEG - 1);
    const int bh  = blk >> 5;
    const int d   = threadIdx.x;
    float off = 0.f;
    for (int c = seg + 1; c < NSEG; ++c)
        off += segsum[(size_t)(bh * NSEG + c) * DD + d];
    float* sp = Sv + ((size_t)bh * SS + seg * 64) * DD + d;
    for (int s = 0; s < 64; ++s) sp[s * DD] += off;
    if (seg == 0)
        Tot[bh * DD + d] = off + segsum[(size_t)(bh * NSEG) * DD + d];
}

// ---------------------------------------------------------------------------
// MFMA causal attention, log-softmax decomposition:
//   out[i,d] = sum_{k<=i} L[i,k] v[k,d] - lse_i*Tot[d] - 1e9*Sv[i,d]
// 128 Q rows/block, 4 waves x 32 rows; 64-wide K tiles, double-buffered async
// global_load_lds staging from pre-swizzled bf16 k / vt tensors.
// ---------------------------------------------------------------------------
__global__ __launch_bounds__(256) void attn_kernel(
    const ushort_t* __restrict__ qb, const ushort_t* __restrict__ kbb,
    const ushort_t* __restrict__ vtb, const float* __restrict__ Sv,
    const float* __restrict__ Tot, const float* __restrict__ pb,
    float* __restrict__ out)
{
    __shared__ __align__(16) ushort_t Ks[2][64 * 64];   // [k][d], swizzled by (k&7)
    __shared__ __align__(16) ushort_t Vt[2][64 * 64];   // [d][k], swizzled by (d&7)
    __shared__ __align__(16) ushort_t Ls[128 * 72];     // [i][k] bf16, wave-private rows
    __shared__ float pbL[2048];                          // pb[h][rel + S-1], rel = i-k >= 0

    const int t = threadIdx.x, w = t >> 6, l = t & 63, ln = t & 15, qd = (t >> 4) & 3;
    const int id = blockIdx.x, bh = id & 31, tt = id >> 5;
    const int qt = (tt < 8) ? (15 - tt) : (tt - 8);   // heavy-first pairing
    const int b = bh >> 4, h = bh & 15, i0 = qt * 128;

    // full pos_bias row slice for this h (rel in [0, 2047])
    {
        const float* p = pb + h * (2 * SS - 1) + (SS - 1);
        *(float4*)&pbL[t * 8]     = *(const float4*)&p[t * 8];
        *(float4*)&pbL[t * 8 + 4] = *(const float4*)&p[t * 8 + 4];
    }

    // Q fragments from global (swizzled bf16), invariant over K loop
    short8 qf[2][2];
    #pragma unroll
    for (int mt = 0; mt < 2; ++mt)
        #pragma unroll
        for (int kh = 0; kh < 2; ++kh) {
            const int i = i0 + 32 * w + 16 * mt + ln;
            qf[mt][kh] = *(const short8*)&qb[((size_t)bh * SS + i) * DD + (((kh * 4 + qd) ^ (ln & 7)) * 8)];
        }

    floatx4 accpv[2][4];
    #pragma unroll
    for (int mt = 0; mt < 2; ++mt)
        #pragma unroll
        for (int ct = 0; ct < 4; ++ct)
            accpv[mt][ct] = (floatx4){0.f, 0.f, 0.f, 0.f};
    float part[2][4] = {};

    const int nkt = 2 * qt + 2;

    auto stage = [&](int buf, int kt) {
        const int k0 = kt * 64;
        #pragma unroll
        for (int j = 0; j < 2; ++j) {
            const int c = w * 2 + j;           // 8 chunks of 8 rows
            const int rk = c * 8 + (l >> 3);
            gl_lds16(&kbb[((size_t)bh * SS + k0 + rk) * DD + (l & 7) * 8], &Ks[buf][c * 512]);
            gl_lds16(&vtb[((size_t)bh * DD + rk) * SS + k0 + (l & 7) * 8], &Vt[buf][c * 512]);
        }
    };

    stage(0, 0);
    for (int kt = 0; kt < nkt; ++kt) {
        __syncthreads();   // drains staged loads; prior-iter readers done
        if (kt + 1 < nkt) stage((kt + 1) & 1, kt + 1);   // prefetch into other buffer
        const ushort_t* KsC = Ks[kt & 1];
        const ushort_t* VtC = Vt[kt & 1];
        const int k0 = kt * 64;

        // QK^T
        floatx4 aq[2][4];
        #pragma unroll
        for (int mt = 0; mt < 2; ++mt)
            #pragma unroll
            for (int ct = 0; ct < 4; ++ct)
                aq[mt][ct] = (floatx4){0.f, 0.f, 0.f, 0.f};
        #pragma unroll
        for (int kh = 0; kh < 2; ++kh) {
            const int sw = ((kh * 4 + qd) ^ (ln & 7)) * 8;
            short8 bfr[4];
            #pragma unroll
            for (int ct = 0; ct < 4; ++ct)
                bfr[ct] = *(const short8*)&KsC[(ct * 16 + ln) * 64 + sw];
            #pragma unroll
            for (int mt = 0; mt < 2; ++mt)
                #pragma unroll
                for (int ct = 0; ct < 4; ++ct)
                    aq[mt][ct] = __builtin_amdgcn_mfma_f32_16x16x32_bf16(qf[mt][kh], bfr[ct], aq[mt][ct], 0, 0, 0);
        }

        // scale + bias (+ mask on diagonal tiles); exp accumulate; P -> Ls bf16
        const int kdiag = i0 - k0;
        if (kt < 2 * qt) {   // fully unmasked tile
            #pragma unroll
            for (int mt = 0; mt < 2; ++mt)
                #pragma unroll
                for (int ct = 0; ct < 4; ++ct) {
                    const int krel = ct * 16 + ln;
                    #pragma unroll
                    for (int reg = 0; reg < 4; ++reg) {
                        const int irel = 32 * w + 16 * mt + qd * 4 + reg;
                        const float val = aq[mt][ct][reg] * 0.125f + pbL[kdiag + irel - krel];
                        part[mt][reg] += __expf(val);
                        Ls[irel * 72 + krel] = f2bf(val);
                    }
                }
        } else {             // diagonal tile: causal mask
            #pragma unroll
            for (int mt = 0; mt < 2; ++mt)
                #pragma unroll
                for (int ct = 0; ct < 4; ++ct) {
                    const int krel = ct * 16 + ln;
                    #pragma unroll
                    for (int reg = 0; reg < 4; ++reg) {
                        const int irel = 32 * w + 16 * mt + qd * 4 + reg;
                        const int rel = kdiag + irel - krel;
                        const bool ok = rel >= 0;
                        const float val = aq[mt][ct][reg] * 0.125f + pbL[ok ? rel : 0];
                        part[mt][reg] += ok ? __expf(val) : 0.f;
                        Ls[irel * 72 + krel] = ok ? f2bf(val) : (ushort_t)0;
                    }
                }
        }

        // PV (Ls rows wave-private: intra-wave DS ordering, no barrier)
        #pragma unroll
        for (int kh = 0; kh < 2; ++kh) {
            const int sw = ((kh * 4 + qd) ^ (ln & 7)) * 8;
            short8 af[2], bfr[4];
            #pragma unroll
            for (int mt = 0; mt < 2; ++mt)
                af[mt] = *(const short8*)&Ls[(32 * w + 16 * mt + ln) * 72 + kh * 32 + qd * 8];
            #pragma unroll
            for (int ct = 0; ct < 4; ++ct)
                bfr[ct] = *(const short8*)&VtC[(ct * 16 + ln) * 64 + sw];
            #pragma unroll
            for (int mt = 0; mt < 2; ++mt)
                #pragma unroll
                for (int ct = 0; ct < 4; ++ct)
                    accpv[mt][ct] = __builtin_amdgcn_mfma_f32_16x16x32_bf16(af[mt], bfr[ct], accpv[mt][ct], 0, 0, 0);
        }
    }

    // row lse via 16-lane shuffle reduction
    float lse[2][4];
    #pragma unroll
    for (int mt = 0; mt < 2; ++mt)
        #pragma unroll
        for (int reg = 0; reg < 4; ++reg) {
            float p = part[mt][reg];
            p += __shfl_xor(p, 1, 64);
            p += __shfl_xor(p, 2, 64);
            p += __shfl_xor(p, 4, 64);
            p += __shfl_xor(p, 8, 64);
            lse[mt][reg] = __logf(p);
        }

    float tot[4];
    #pragma unroll
    for (int ct = 0; ct < 4; ++ct) tot[ct] = Tot[bh * DD + ct * 16 + ln];

    #pragma unroll
    for (int mt = 0; mt < 2; ++mt)
        #pragma unroll
        for (int ct = 0; ct < 4; ++ct) {
            const int d = ct * 16 + ln;
            #pragma unroll
            for (int reg = 0; reg < 4; ++reg) {
                const int ig = i0 + 32 * w + 16 * mt + qd * 4 + reg;
                const float sv = Sv[((size_t)bh * SS + ig) * DD + d];
                const float o = accpv[mt][ct][reg] - lse[mt][reg] * tot[ct] - 1e9f * sv;
                out[((size_t)(b * SS + ig)) * EE + h * DD + d] = o;
            }
        }
}

// ---------------------------------------------------------------------------
extern "C" void kernel_launch(void* const* d_in, const int* in_sizes, int n_in,
                              void* d_out, int out_size, void* d_ws, size_t ws_size,
                              hipStream_t stream)
{
    const float* query = (const float*)d_in[0];
    const float* key_  = (const float*)d_in[1];
    const float* value = (const float*)d_in[2];
    const float* Wq = (const float*)d_in[3];
    const float* bq = (const float*)d_in[4];
    const float* Wk = (const float*)d_in[5];
    const float* bk = (const float*)d_in[6];
    const float* Wv = (const float*)d_in[7];
    const float* bv = (const float*)d_in[8];
    const float* pb = (const float*)d_in[9];
    float* out = (float*)d_out;

    float* ws = (float*)d_ws;
    const size_t SZ = (size_t)BB * SS * EE;         // 4M elements
    float* vf   = ws;                                // fp32 v [bh][s][d]
    float* Svb  = ws + SZ;
    float* Totb = ws + 2 * SZ;
    float* segs = Totb + BB * HH * DD;
    ushort_t* us  = (ushort_t*)(segs + (size_t)BB * HH * NSEG * DD);
    ushort_t* qbp = us;                              // bf16 swizzled q [bh][s][d]
    ushort_t* kbp = qbp + SZ;                        // bf16 swizzled k [bh][s][d]
    ushort_t* vtp = kbp + SZ;                        // bf16 swizzled vt [bh][d][s]
    ushort_t* Xbf = vtp + SZ;                        // 3 x (B*S x E)
    ushort_t* Wbf = Xbf + 3 * SZ;                    // 3 x (E x E)

    repack_kernel<<<dim3((unsigned)(SZ / 8 / 256), 1, 3), 256, 0, stream>>>(
        query, key_, value, Xbf, BB * SS);
    repack_kernel<<<dim3((unsigned)((size_t)EE * EE / 8 / 256), 1, 3), 256, 0, stream>>>(
        Wq, Wk, Wv, Wbf, EE);

    proj_kernel<<<dim3(BB * SS / 128, EE / 128, 3), 256, 0, stream>>>(
        Xbf, Wbf, bq, bk, bv, qbp, kbp, vf, vtp);

    scan_partial<<<BB * HH * NSEG, 64, 0, stream>>>(vf, Svb, segs);
    scan_finalize<<<BB * HH * NSEG, 64, 0, stream>>>(Svb, segs, Totb);

    attn_kernel<<<BB * HH * (SS / 128), 256, 0, stream>>>(
        qbp, kbp, vtp, Svb, Totb, pb, out);
}